// Round 6
// baseline (68.980 us; speedup 1.0000x reference)
//
#include <hip/hip_runtime.h>

#define NQ 14
#define BLOCK 512
#define NG 28
#define NF2 16  // f32x2 regs per thread (32 amps)

typedef float f32x2 __attribute__((ext_vector_type(2)));
__device__ __forceinline__ f32x2 mk2(float a, float b) { f32x2 r; r.x = a; r.y = b; return r; }

// ---------------- compile-time schedule (lazy-CNOT folding) ----------------
struct Sched { unsigned m[NG]; unsigned r[NG]; unsigned fr[NQ]; };

constexpr Sched build_sched() {
  Sched sc{};
  unsigned col[NQ] = {}, rowinv[NQ] = {};
  for (int p = 0; p < NQ; ++p) { col[p] = 1u << p; rowinv[p] = 1u << p; }
  int g = 0;
  for (int l = 0; l < 2; ++l) {
    for (int w = 0; w < NQ; ++w) { int p = NQ - 1 - w; sc.m[g] = col[p]; sc.r[g] = rowinv[p]; ++g; }
    for (int w = 0; w < NQ; ++w) {
      int tgt = (w + 1) % NQ; int pc = NQ - 1 - w, pt = NQ - 1 - tgt;
      col[pc] ^= col[pt]; rowinv[pt] ^= rowinv[pc];
    }
  }
  for (int w = 0; w < NQ; ++w) sc.fr[w] = rowinv[NQ - 1 - w];
  return sc;
}
constexpr Sched SC = build_sched();

// Gates 0..13 (layer-0 weights) absorbed into the fill: RY(w0)RY(x)|0> =
// RY(x+w0)|0>. Remaining gates g14..g27 run in ORIGINAL order, bucketed:
//   P1: g14..g17 (span bits 9..13)   P2: g18..g21 (span 5..9)
//   P3: g22..g25 (span 1..5)         P4: g26..g27 (span {0,1,2,12,13})
constexpr unsigned SPAN[4] = {0x3E00u, 0x03E0u, 0x003Eu, 0x3007u};

// local-coordinate maps: local index l = (p<<1)|e, e = f32x2 component
constexpr unsigned lmap1(unsigned v) { return ((v >> 9) & 1u) | (((v >> 10) & 15u) << 1); }
constexpr unsigned lmap2(unsigned v) { return ((v >> 9) & 1u) | (((v >> 5) & 15u) << 1); }
constexpr unsigned lmap3(unsigned v) { return ((v >> 5) & 1u) | (((v >> 1) & 15u) << 1); }
constexpr unsigned lmap4(unsigned v) { return (v & 1u) | (((v >> 1) & 3u) << 1) | (((v >> 12) & 3u) << 3); }

// ------------- phase layouts: (thread t<512, reg p<16, comp e<2) -> i -------------
__host__ __device__ constexpr unsigned i1(unsigned t, unsigned p, unsigned e) { return t | (e << 9) | (p << 10); }
__host__ __device__ constexpr unsigned i2(unsigned t, unsigned p, unsigned e) {
  return (t & 31u) | (p << 5) | (e << 9) | ((t >> 5) << 10);
}
__host__ __device__ constexpr unsigned i3(unsigned t, unsigned p, unsigned e) {
  return (t & 1u) | (p << 1) | (e << 5) | ((t >> 1) << 6);
}
__host__ __device__ constexpr unsigned i4(unsigned t, unsigned p, unsigned e) {
  return e | ((p & 3u) << 1) | (t << 3) | ((p >> 2) << 12);
}
// thread-part (local bits zeroed) per phase; asserted == iP(t,0,0)
__host__ __device__ constexpr unsigned base1(unsigned t) { return t; }
__host__ __device__ constexpr unsigned base2(unsigned t) { return (t & 31u) | ((t >> 5) << 10); }
__host__ __device__ constexpr unsigned base3(unsigned t) { return (t & 1u) | ((t >> 1) << 6); }
__host__ __device__ constexpr unsigned base4(unsigned t) { return t << 3; }

// ------------- storage maps (dword addr of state index i) — single source of
// truth, used verbatim by BOTH device code and the static_asserts. -------------
__host__ __device__ constexpr unsigned st1(unsigned i) {  // T1: P1 -> P2
  return 32u * (i & 511u) + (((i >> 9) & 31u) ^ (i & 31u));
}
__host__ __device__ constexpr unsigned st2(unsigned i) {  // T2: P2 -> P3
  const unsigned t = (i & 31u) | (((i >> 10) & 15u) << 5);
  const unsigned l = (i >> 5) & 31u;
  return 32u * t + (l ^ (t & 31u));
}
__host__ __device__ constexpr unsigned st3(unsigned i) {  // T3: P3 -> P4
  const unsigned t = (i & 1u) | (((i >> 6) & 255u) << 1);
  const unsigned l = ((i >> 1) & 15u) | (((i >> 5) & 1u) << 4);
  return 32u * t + (l ^ (t & 31u) ^ ((l >> 2) & 1u));  // extra bit0 mix: fixes P4-read banks
}

// ---------------- machine checks ----------------
constexpr bool sched_ok() {
  for (int g = 0; g < 14; ++g)  // absorbability of layer-0
    if (SC.m[g] != (1u << (13 - g)) || SC.r[g] != (1u << (13 - g))) return false;
  for (int g = 14; g < 28; ++g) {
    const int ph = (g < 18) ? 0 : (g < 22) ? 1 : (g < 26) ? 2 : 3;
    if (SC.m[g] & ~SPAN[ph]) return false;  // pairing mask must be phase-local
    unsigned lm = 0, lr = 0;
    if (ph == 0) { lm = lmap1(SC.m[g]); lr = lmap1(SC.r[g]); }
    if (ph == 1) { lm = lmap2(SC.m[g]); lr = lmap2(SC.r[g]); }
    if (ph == 2) { lm = lmap3(SC.m[g]); lr = lmap3(SC.r[g]); }
    if (ph == 3) { lm = lmap4(SC.m[g]); lr = lmap4(SC.r[g]); }
    if (lm == 0) return false;
    if (!(__builtin_popcount(lm & lr) & 1)) return false;  // sigma(l^mu) = -sigma(l)
  }
  return true;  // execution order == original order: no commutation needed
}
static_assert(sched_ok(), "schedule invalid");

constexpr unsigned iP(int ph, unsigned t, unsigned p, unsigned e) {
  return ph == 0 ? i1(t, p, e) : ph == 1 ? i2(t, p, e) : ph == 2 ? i3(t, p, e) : i4(t, p, e);
}
constexpr bool layouts_ok() {
  for (int ph = 0; ph < 4; ++ph) {
    unsigned acc = 0;
    for (int k = 0; k < 14; ++k) {  // disjoint-shifted-field maps: basis test = bijectivity
      unsigned t = 0, p = 0, e = 0;
      if (k < 9) t = 1u << k; else if (k < 13) p = 1u << (k - 9); else e = 1;
      const unsigned v = iP(ph, t, p, e);
      if (__builtin_popcount(v) != 1 || (acc & v)) return false;
      acc |= v;
    }
    if (acc != 0x3FFFu) return false;
  }
  for (unsigned t = 0; t < 512; ++t) {
    if (base1(t) != i1(t, 0, 0)) return false;
    if (base2(t) != i2(t, 0, 0)) return false;
    if (base3(t) != i3(t, 0, 0)) return false;
    if (base4(t) != i4(t, 0, 0)) return false;
  }
  return true;
}
static_assert(layouts_ok(), "phase layouts invalid");

constexpr bool stmap_bij(int which) {
  bool hit[16384] = {};
  for (unsigned i = 0; i < 16384; ++i) {
    const unsigned a = which == 0 ? st1(i) : which == 1 ? st2(i) : st3(i);
    if (a >= 16384u || hit[a]) return false;
    hit[a] = true;
  }
  return true;
}
static_assert(stmap_bij(0), "st1 not bijective");
static_assert(stmap_bij(1), "st2 not bijective");
static_assert(stmap_bij(2), "st3 not bijective");

// exhaustive bank check: every transpose side, every unrolled step, every wave:
// max 2 lanes per bank (2-way aliasing is free on gfx950 — m136)
constexpr bool banks_ok(int pat) {
  for (unsigned pe = 0; pe < 32; ++pe) {
    const unsigned p = pe >> 1, e = pe & 1;
    for (unsigned W = 0; W < 8; ++W) {
      int cnt[32] = {};
      for (unsigned lane = 0; lane < 64; ++lane) {
        const unsigned t = W * 64 + lane;
        const unsigned a = pat == 0 ? st1(i1(t, p, e))
                         : pat == 1 ? st1(i2(t, p, e))
                         : pat == 2 ? st2(i2(t, p, e))
                         : pat == 3 ? st2(i3(t, p, e))
                         : pat == 4 ? st3(i3(t, p, e))
                                    : st3(i4(t, p, e));
        if (++cnt[a & 31u] > 2) return false;
      }
    }
  }
  return true;
}
static_assert(banks_ok(0), "T1 write banks");
static_assert(banks_ok(1), "T1 read banks");
static_assert(banks_ok(2), "T2 write banks");
static_assert(banks_ok(3), "T2 read banks");
static_assert(banks_ok(4), "T3 write banks");
static_assert(banks_ok(5), "T3 read banks");

// ---------------- packed register butterfly (5-bit local, 16 f32x2) ----------------
// v[l]' = c*v[l] - sigma(l)*sb*v[l^MU], sigma(l) = parity(l&RHO) ? -1 : +1
template <unsigned MU, unsigned RHO>
__device__ __forceinline__ void gate_pk(f32x2* v, const float cg, const float sb) {
  const f32x2 C = mk2(cg, cg);
  constexpr unsigned M2 = MU >> 1;
  constexpr bool ODD = (MU & 1u) != 0;
  if constexpr (!ODD) {
    constexpr unsigned LSB = M2 & (0u - M2);
#pragma unroll
    for (unsigned p = 0; p < NF2; ++p) {
      if (p & LSB) continue;
      const unsigned q = p ^ M2;
      const int s0 = __builtin_popcount((2u * p) & RHO) & 1;
      const int s1 = __builtin_popcount((2u * p + 1u) & RHO) & 1;
      const f32x2 Sp = mk2(s0 ? -sb : sb, s1 ? -sb : sb);
      const f32x2 Xp = v[p], Xq = v[q];
      v[p] = C * Xp - Sp * Xq;
      v[q] = C * Xq + Sp * Xp;  // sigma(l^MU) = -sigma(l)
    }
  } else if constexpr (M2 == 0) {  // MU==1: within-component-pair butterfly
#pragma unroll
    for (unsigned p = 0; p < NF2; ++p) {
      const int s0 = __builtin_popcount((2u * p) & RHO) & 1;
      const f32x2 Sp = mk2(s0 ? -sb : sb, s0 ? sb : -sb);
      const f32x2 X = v[p];
      v[p] = C * X - Sp * mk2(X.y, X.x);
    }
  } else {  // MU odd: crosses component AND registers
    constexpr unsigned LSB = M2 & (0u - M2);
#pragma unroll
    for (unsigned p = 0; p < NF2; ++p) {
      if (p & LSB) continue;
      const unsigned q = p ^ M2;
      const int s0 = __builtin_popcount((2u * p) & RHO) & 1;
      const int s1 = __builtin_popcount((2u * p + 1u) & RHO) & 1;
      const f32x2 Sp = mk2(s0 ? -sb : sb, s1 ? -sb : sb);
      const f32x2 Xp = v[p], Xq = v[q];
      const f32x2 T = Sp * Xp;
      v[p] = C * Xp - Sp * mk2(Xq.y, Xq.x);
      v[q] = C * Xq + mk2(T.y, T.x);
    }
  }
}

__global__ __launch_bounds__(BLOCK, 4) void qnn_kernel(
    const float* __restrict__ x, const float* __restrict__ wts,
    float* __restrict__ out) {
  __shared__ float S[16384];  // 64 KB: transpose medium + final reduction
  const unsigned t = threadIdx.x;
  const int b = blockIdx.x;

  f32x2 v2[NF2];

  // ---- Fill: RY(x + weights[0]) product state, P1 layout ----
  // state bit 13-w <-> wire w: thread bits 0..8 = wires 13..5; e(bit9)=wire4;
  // p bit k (state bit 10+k) = wire 3-k.
  {
    float cxx[NQ], sxx[NQ];
#pragma unroll
    for (int w = 0; w < NQ; ++w)
      __sincosf(0.5f * (x[b * NQ + w] + wts[w]), &sxx[w], &cxx[w]);
    float pl = 1.0f;
#pragma unroll
    for (int bb = 0; bb < 9; ++bb) pl *= ((t >> bb) & 1) ? sxx[13 - bb] : cxx[13 - bb];
    v2[0] = mk2(pl * cxx[4], pl * sxx[4]);
#pragma unroll
    for (int k = 0; k < 4; ++k) {
      const int K = 1 << k;
      const float sk = sxx[3 - k], ck = cxx[3 - k];
#pragma unroll
      for (int j = K - 1; j >= 0; --j) {
        v2[j | K] = v2[j] * mk2(sk, sk);
        v2[j] = v2[j] * mk2(ck, ck);
      }
    }
  }

#define RUN_GATE(LM, G, BASEPAR)                                          \
  {                                                                       \
    float sn, cs;                                                         \
    __sincosf(0.5f * wts[G], &sn, &cs);                                   \
    const float sb =                                                      \
        (__builtin_popcount((BASEPAR) & SC.r[G]) & 1) ? -sn : sn;         \
    gate_pk<LM(SC.m[G]), LM(SC.r[G])>(v2, cs, sb);                        \
  }

  // ---------------- Phase 1: span {9..13} ----------------
  {
    const unsigned bs = base1(t);
    RUN_GATE(lmap1, 14, bs) RUN_GATE(lmap1, 15, bs)
    RUN_GATE(lmap1, 16, bs) RUN_GATE(lmap1, 17, bs)
#pragma unroll
    for (unsigned p = 0; p < NF2; ++p) {
      S[st1(i1(t, p, 0))] = v2[p].x;
      S[st1(i1(t, p, 1))] = v2[p].y;
    }
  }
  __syncthreads();  // A

  // ---------------- Phase 2: span {5..9} ----------------
  {
    const unsigned bs = base2(t);
#pragma unroll
    for (unsigned p = 0; p < NF2; ++p) {
      v2[p].x = S[st1(i2(t, p, 0))];
      v2[p].y = S[st1(i2(t, p, 1))];
    }
    RUN_GATE(lmap2, 18, bs) RUN_GATE(lmap2, 19, bs)
    RUN_GATE(lmap2, 20, bs) RUN_GATE(lmap2, 21, bs)
  }
  __syncthreads();  // B: all T1 reads done before storage reuse
  {
#pragma unroll
    for (unsigned p = 0; p < NF2; ++p) {
      S[st2(i2(t, p, 0))] = v2[p].x;
      S[st2(i2(t, p, 1))] = v2[p].y;
    }
  }
  __syncthreads();  // C

  // ---------------- Phase 3: span {1..5} ----------------
  {
    const unsigned bs = base3(t);
#pragma unroll
    for (unsigned p = 0; p < NF2; ++p) {
      v2[p].x = S[st2(i3(t, p, 0))];
      v2[p].y = S[st2(i3(t, p, 1))];
    }
    RUN_GATE(lmap3, 22, bs) RUN_GATE(lmap3, 23, bs)
    RUN_GATE(lmap3, 24, bs) RUN_GATE(lmap3, 25, bs)
  }
  __syncthreads();  // D: all T2 reads done
  {
#pragma unroll
    for (unsigned p = 0; p < NF2; ++p) {
      S[st3(i3(t, p, 0))] = v2[p].x;
      S[st3(i3(t, p, 1))] = v2[p].y;
    }
  }
  __syncthreads();  // E

  // ---------------- Phase 4: span {0,1,2,12,13} + measurement ----------------
  float ex[NQ];
  {
    const unsigned bs = base4(t);
#pragma unroll
    for (unsigned p = 0; p < NF2; ++p) {
      v2[p].x = S[st3(i4(t, p, 0))];
      v2[p].y = S[st3(i4(t, p, 1))];
    }
    RUN_GATE(lmap4, 26, bs) RUN_GATE(lmap4, 27, bs)

    // q = v^2; WHT over p bits (4 levels); e-level folded into extraction
#pragma unroll
    for (unsigned p = 0; p < NF2; ++p) v2[p] = v2[p] * v2[p];
#pragma unroll
    for (int k = 0; k < 4; ++k) {
      const unsigned K = 1u << k;
#pragma unroll
      for (unsigned p = 0; p < NF2; ++p) {
        if (p & K) continue;
        const f32x2 A = v2[p], Bv = v2[p ^ K];
        v2[p] = A + Bv;
        v2[p ^ K] = A - Bv;
      }
    }
#pragma unroll
    for (int w = 0; w < NQ; ++w) {
      const unsigned ls = lmap4(SC.fr[w]);
      const f32x2 W = v2[ls >> 1];
      const float coef = (ls & 1u) ? (W.x - W.y) : (W.x + W.y);
      const int tf = __builtin_popcount(bs & SC.fr[w]) & 1;
      ex[w] = tf ? -coef : coef;
    }
  }

  // ---------------- block reduction (8 waves) ----------------
#pragma unroll
  for (int w = 0; w < NQ; ++w) {
#pragma unroll
    for (int off = 32; off > 0; off >>= 1) ex[w] += __shfl_xor(ex[w], off, 64);
  }
  __syncthreads();  // F: all T3 reads done; S reusable
  const unsigned lane = t & 63u, wv = t >> 6;
  if (lane == 0) {
#pragma unroll
    for (int w = 0; w < NQ; ++w) S[wv * NQ + w] = ex[w];
  }
  __syncthreads();  // G
  if (t < NQ) {
    float r = 0.0f;
#pragma unroll
    for (int W = 0; W < 8; ++W) r += S[W * NQ + t];
    out[b * NQ + t] = r;
  }
#undef RUN_GATE
}

extern "C" void kernel_launch(void* const* d_in, const int* in_sizes, int n_in,
                              void* d_out, int out_size, void* d_ws, size_t ws_size,
                              hipStream_t stream) {
  const float* x = (const float*)d_in[0];        // (B, 14) fp32
  const float* weights = (const float*)d_in[1];  // (2, 14) fp32
  float* out = (float*)d_out;                    // (B, 14) fp32
  const int B = in_sizes[0] / NQ;
  qnn_kernel<<<B, BLOCK, 0, stream>>>(x, weights, out);
}

// Round 7
// 65.835 us; speedup vs baseline: 1.0478x; 1.0478x over previous
//
#include <hip/hip_runtime.h>

#define NQ 14
#define BLOCK 512
#define NG 28
#define NF2 16  // f32x2 regs per thread (32 amps)

typedef float f32x2 __attribute__((ext_vector_type(2)));
__device__ __forceinline__ f32x2 mk2(float a, float b) { f32x2 r; r.x = a; r.y = b; return r; }

// ---------------- compile-time schedule (lazy-CNOT folding) ----------------
struct Sched { unsigned m[NG]; unsigned r[NG]; unsigned fr[NQ]; };

constexpr Sched build_sched() {
  Sched sc{};
  unsigned col[NQ] = {}, rowinv[NQ] = {};
  for (int p = 0; p < NQ; ++p) { col[p] = 1u << p; rowinv[p] = 1u << p; }
  int g = 0;
  for (int l = 0; l < 2; ++l) {
    for (int w = 0; w < NQ; ++w) { int p = NQ - 1 - w; sc.m[g] = col[p]; sc.r[g] = rowinv[p]; ++g; }
    for (int w = 0; w < NQ; ++w) {
      int tgt = (w + 1) % NQ; int pc = NQ - 1 - w, pt = NQ - 1 - tgt;
      col[pc] ^= col[pt]; rowinv[pt] ^= rowinv[pc];
    }
  }
  for (int w = 0; w < NQ; ++w) sc.fr[w] = rowinv[NQ - 1 - w];
  return sc;
}
constexpr Sched SC = build_sched();

// Gates 0..13 (layer-0 weights) absorbed into fill: RY(w0)RY(x)|0> = RY(x+w0)|0>.
// Remaining g14..g27 in ORIGINAL order, bucketed by span:
//   P1: g14-17 {9..13}  P2: g18-21 {5..9}  P3: g22-25 {1..5}  P4: g26-27 {0,1,2,12,13}
constexpr unsigned SPAN[4] = {0x3E00u, 0x03E0u, 0x003Eu, 0x3007u};

// local maps: l = (p<<1)|e; e = f32x2 component
constexpr unsigned lmap1(unsigned v) { return ((v >> 9) & 1u) | (((v >> 10) & 15u) << 1); }  // e=bit9
constexpr unsigned lmap2(unsigned v) { return ((v >> 9) & 1u) | (((v >> 5) & 15u) << 1); }   // e=bit9
constexpr unsigned lmap3(unsigned v) { return ((v >> 5) & 1u) | (((v >> 1) & 15u) << 1); }   // e=bit5
// P4: e=bit1, p0=bit2, p1=bit0, p2,p3=bits12,13  (e moved to bit1 for b128 T3)
constexpr unsigned lmap4(unsigned v) {
  return ((v >> 1) & 1u) | (((v >> 2) & 1u) << 1) | ((v & 1u) << 2) | (((v >> 12) & 3u) << 3);
}

// ---------- phase layouts: (thread t<512, reg p<16, comp e<2) -> state i ----------
__host__ __device__ constexpr unsigned i1(unsigned t, unsigned p, unsigned e) { return t | (e << 9) | (p << 10); }
__host__ __device__ constexpr unsigned i2(unsigned t, unsigned p, unsigned e) {
  return (t & 31u) | (p << 5) | (e << 9) | ((t >> 5) << 10);
}
__host__ __device__ constexpr unsigned i3(unsigned t, unsigned p, unsigned e) {
  return (t & 1u) | (p << 1) | (e << 5) | ((t >> 1) << 6);
}
__host__ __device__ constexpr unsigned i4(unsigned t, unsigned p, unsigned e) {
  return ((p >> 1) & 1u) | (e << 1) | ((p & 1u) << 2) | (t << 3) | (((p >> 2) & 3u) << 12);
}
__host__ __device__ constexpr unsigned base1(unsigned t) { return t; }
__host__ __device__ constexpr unsigned base2(unsigned t) { return (t & 31u) | ((t >> 5) << 10); }
__host__ __device__ constexpr unsigned base3(unsigned t) { return (t & 1u) | ((t >> 1) << 6); }
__host__ __device__ constexpr unsigned base4(unsigned t) { return t << 3; }

// ---------- storage maps: dword addr of state i; low-2 addr bits chosen so
// BOTH sides access contiguously (b128 writes, b64/b128 reads). Single source
// of truth: device code calls these SAME constexpr fns the asserts evaluate. ----------
__host__ __device__ constexpr unsigned a1(unsigned i) {  // T1: P1->P2. low2 = {bit9, bit10}
  const unsigned tA = i & 511u, jA = (i >> 11) & 7u;
  return 4u * (tA * 8u + (jA ^ (tA & 7u))) + ((i >> 9) & 1u) + 2u * ((i >> 10) & 1u);
}
__host__ __device__ constexpr unsigned a2(unsigned i) {  // T2: P2->P3. low2 = {bit5, bit9}
  const unsigned tB = (i & 31u) | (((i >> 10) & 15u) << 5);
  const unsigned jB = (i >> 6) & 7u;
  return 4u * (tB * 8u + (jB ^ (tB & 7u))) + ((i >> 5) & 1u) + 2u * ((i >> 9) & 1u);
}
__host__ __device__ constexpr unsigned a3(unsigned i) {  // T3: P3->P4. low2 = {bit1, bit2}
  const unsigned tC = (i >> 3) & 511u;
  const unsigned kC = (i & 1u) | (((i >> 12) & 3u) << 1);
  return 4u * (tC * 8u + (kC ^ ((i >> 6) & 7u))) + ((i >> 1) & 1u) + 2u * ((i >> 2) & 1u);
}

// ---------------- machine checks ----------------
constexpr bool sched_ok() {
  for (int g = 0; g < 14; ++g)
    if (SC.m[g] != (1u << (13 - g)) || SC.r[g] != (1u << (13 - g))) return false;
  for (int g = 14; g < 28; ++g) {
    const int ph = (g < 18) ? 0 : (g < 22) ? 1 : (g < 26) ? 2 : 3;
    if (SC.m[g] & ~SPAN[ph]) return false;
    unsigned lm = 0, lr = 0;
    if (ph == 0) { lm = lmap1(SC.m[g]); lr = lmap1(SC.r[g]); }
    if (ph == 1) { lm = lmap2(SC.m[g]); lr = lmap2(SC.r[g]); }
    if (ph == 2) { lm = lmap3(SC.m[g]); lr = lmap3(SC.r[g]); }
    if (ph == 3) { lm = lmap4(SC.m[g]); lr = lmap4(SC.r[g]); }
    if (lm == 0) return false;
    if (!(__builtin_popcount(lm & lr) & 1)) return false;
  }
  return true;  // original order preserved: no commutation requirement
}
static_assert(sched_ok(), "schedule invalid");

constexpr unsigned iP(int ph, unsigned t, unsigned p, unsigned e) {
  return ph == 0 ? i1(t, p, e) : ph == 1 ? i2(t, p, e) : ph == 2 ? i3(t, p, e) : i4(t, p, e);
}
constexpr bool layouts_ok() {
  for (int ph = 0; ph < 4; ++ph) {
    unsigned acc = 0;
    for (int k = 0; k < 14; ++k) {
      unsigned t = 0, p = 0, e = 0;
      if (k < 9) t = 1u << k; else if (k < 13) p = 1u << (k - 9); else e = 1;
      const unsigned v = iP(ph, t, p, e);
      if (__builtin_popcount(v) != 1 || (acc & v)) return false;
      acc |= v;
    }
    if (acc != 0x3FFFu) return false;
  }
  for (unsigned t = 0; t < 512; ++t) {
    if (base1(t) != i1(t, 0, 0) || base2(t) != i2(t, 0, 0)) return false;
    if (base3(t) != i3(t, 0, 0) || base4(t) != i4(t, 0, 0)) return false;
  }
  return true;
}
static_assert(layouts_ok(), "phase layouts invalid");

constexpr bool stmap_bij(int which) {
  bool hit[16384] = {};
  for (unsigned i = 0; i < 16384; ++i) {
    const unsigned a = which == 0 ? a1(i) : which == 1 ? a2(i) : a3(i);
    if (a >= 16384u || hit[a]) return false;
    hit[a] = true;
  }
  return true;
}
static_assert(stmap_bij(0), "a1 not bijective");
static_assert(stmap_bij(1), "a2 not bijective");
static_assert(stmap_bij(2), "a3 not bijective");

// contiguity/alignment of every access, every thread
constexpr bool contig_ok(unsigned t0, unsigned t1) {
  for (unsigned t = t0; t < t1; ++t) {
    for (unsigned j = 0; j < 8; ++j) {
      const unsigned b1 = a1(i1(t, 2 * j, 0));            // T1 write b128: +2q+e
      if (b1 % 4 != 0) return false;
      for (unsigned q = 0; q < 2; ++q) for (unsigned e = 0; e < 2; ++e)
        if (a1(i1(t, 2 * j + q, e)) != b1 + 2 * q + e) return false;
      const unsigned b2 = a2(i2(t, 2 * j, 0));            // T2 write b128: +q+2e
      if (b2 % 4 != 0) return false;
      for (unsigned q = 0; q < 2; ++q) for (unsigned e = 0; e < 2; ++e)
        if (a2(i2(t, 2 * j + q, e)) != b2 + q + 2 * e) return false;
      const unsigned b4 = a3(i4(t, 2 * j, 0));            // T3 read b128: +2q+e
      if (b4 % 4 != 0) return false;
      for (unsigned q = 0; q < 2; ++q) for (unsigned e = 0; e < 2; ++e)
        if (a3(i4(t, 2 * j + q, e)) != b4 + 2 * q + e) return false;
    }
    for (unsigned j = 0; j < 4; ++j) for (unsigned e = 0; e < 2; ++e) {
      const unsigned b3 = a3(i3(t, 4 * j, e));            // T3 write b128: +q
      if (b3 % 4 != 0) return false;
      for (unsigned q = 0; q < 4; ++q)
        if (a3(i3(t, 4 * j + q, e)) != b3 + q) return false;
    }
    for (unsigned p = 0; p < 16; ++p) {
      const unsigned r1 = a1(i2(t, p, 0));                // T1 read b64
      if (r1 % 2 != 0 || a1(i2(t, p, 1)) != r1 + 1) return false;
      const unsigned r2 = a2(i3(t, p, 0));                // T2 read b64
      if (r2 % 2 != 0 || a2(i3(t, p, 1)) != r2 + 1) return false;
    }
  }
  return true;
}
static_assert(contig_ok(0, 64) && contig_ok(64, 128), "contig 0-128");
static_assert(contig_ok(128, 192) && contig_ok(192, 256), "contig 128-256");
static_assert(contig_ok(256, 320) && contig_ok(320, 384), "contig 256-384");
static_assert(contig_ok(384, 448) && contig_ok(448, 512), "contig 384-512");

// bank balance at the bandwidth floor: b128 <=8 lanes/bank-group, b64 <=4/pair
constexpr bool banks128(int pat) {  // 0=T1w 1=T2w 2=T3w 3=T3r
  for (unsigned W = 0; W < 8; ++W)
    for (unsigned j = 0; j < 8; ++j) {
      int cnt[8] = {};
      for (unsigned l = 0; l < 64; ++l) {
        const unsigned t = W * 64u + l;
        unsigned a = 0;
        if (pat == 0) a = a1(i1(t, 2 * j, 0));
        if (pat == 1) a = a2(i2(t, 2 * j, 0));
        if (pat == 2) a = a3(i3(t, 4 * (j >> 1), j & 1));
        if (pat == 3) a = a3(i4(t, 2 * j, 0));
        if (++cnt[(a >> 2) & 7u] > 8) return false;
      }
    }
  return true;
}
constexpr bool banks64(int pat) {  // 0=T1r 1=T2r
  for (unsigned W = 0; W < 8; ++W)
    for (unsigned p = 0; p < 16; ++p) {
      int cnt[16] = {};
      for (unsigned l = 0; l < 64; ++l) {
        const unsigned t = W * 64u + l;
        const unsigned a = (pat == 0) ? a1(i2(t, p, 0)) : a2(i3(t, p, 0));
        if (++cnt[(a >> 1) & 15u] > 4) return false;
      }
    }
  return true;
}
static_assert(banks128(0), "T1w banks");
static_assert(banks128(1), "T2w banks");
static_assert(banks128(2), "T3w banks");
static_assert(banks128(3), "T3r banks");
static_assert(banks64(0), "T1r banks");
static_assert(banks64(1), "T2r banks");

// ---------------- packed register butterfly (5-bit local) ----------------
template <unsigned MU, unsigned RHO>
__device__ __forceinline__ void gate_pk(f32x2* v, const float cg, const float sb) {
  const f32x2 C = mk2(cg, cg);
  constexpr unsigned M2 = MU >> 1;
  constexpr bool ODD = (MU & 1u) != 0;
  if constexpr (!ODD) {
    constexpr unsigned LSB = M2 & (0u - M2);
#pragma unroll
    for (unsigned p = 0; p < NF2; ++p) {
      if (p & LSB) continue;
      const unsigned q = p ^ M2;
      const int s0 = __builtin_popcount((2u * p) & RHO) & 1;
      const int s1 = __builtin_popcount((2u * p + 1u) & RHO) & 1;
      const f32x2 Sp = mk2(s0 ? -sb : sb, s1 ? -sb : sb);
      const f32x2 Xp = v[p], Xq = v[q];
      v[p] = C * Xp - Sp * Xq;
      v[q] = C * Xq + Sp * Xp;
    }
  } else if constexpr (M2 == 0) {
#pragma unroll
    for (unsigned p = 0; p < NF2; ++p) {
      const int s0 = __builtin_popcount((2u * p) & RHO) & 1;
      const f32x2 Sp = mk2(s0 ? -sb : sb, s0 ? sb : -sb);
      const f32x2 X = v[p];
      v[p] = C * X - Sp * mk2(X.y, X.x);
    }
  } else {
    constexpr unsigned LSB = M2 & (0u - M2);
#pragma unroll
    for (unsigned p = 0; p < NF2; ++p) {
      if (p & LSB) continue;
      const unsigned q = p ^ M2;
      const int s0 = __builtin_popcount((2u * p) & RHO) & 1;
      const int s1 = __builtin_popcount((2u * p + 1u) & RHO) & 1;
      const f32x2 Sp = mk2(s0 ? -sb : sb, s1 ? -sb : sb);
      const f32x2 Xp = v[p], Xq = v[q];
      const f32x2 T = Sp * Xp;
      v[p] = C * Xp - Sp * mk2(Xq.y, Xq.x);
      v[q] = C * Xq + mk2(T.y, T.x);
    }
  }
}

__global__ __launch_bounds__(BLOCK, 4) void qnn_kernel(
    const float* __restrict__ x, const float* __restrict__ wts,
    float* __restrict__ out) {
  __shared__ float4 S4[4096];  // 64 KB, 16B-aligned
  float* const S = (float*)S4;
  float4* const F4 = S4;
  const f32x2* const Fv = (const f32x2*)S4;
  const unsigned t = threadIdx.x;
  const int b = blockIdx.x;

  f32x2 v2[NF2];

  // ---- Fill: RY(x + weights[0]) product state, P1 layout ----
  {
    float cxx[NQ], sxx[NQ];
#pragma unroll
    for (int w = 0; w < NQ; ++w)
      __sincosf(0.5f * (x[b * NQ + w] + wts[w]), &sxx[w], &cxx[w]);
    float pl = 1.0f;
#pragma unroll
    for (int bb = 0; bb < 9; ++bb) pl *= ((t >> bb) & 1) ? sxx[13 - bb] : cxx[13 - bb];
    v2[0] = mk2(pl * cxx[4], pl * sxx[4]);
#pragma unroll
    for (int k = 0; k < 4; ++k) {
      const int K = 1 << k;
      const float sk = sxx[3 - k], ck = cxx[3 - k];
#pragma unroll
      for (int j = K - 1; j >= 0; --j) {
        v2[j | K] = v2[j] * mk2(sk, sk);
        v2[j] = v2[j] * mk2(ck, ck);
      }
    }
  }

#define RUN_GATE(LM, G, BASEPAR)                                          \
  {                                                                       \
    float sn, cs;                                                         \
    __sincosf(0.5f * wts[G], &sn, &cs);                                   \
    const float sb =                                                      \
        (__builtin_popcount((BASEPAR) & SC.r[G]) & 1) ? -sn : sn;         \
    gate_pk<LM(SC.m[G]), LM(SC.r[G])>(v2, cs, sb);                        \
  }

  // ---------------- Phase 1: span {9..13} ----------------
  {
    const unsigned bs = base1(t);
    RUN_GATE(lmap1, 14, bs) RUN_GATE(lmap1, 15, bs)
    RUN_GATE(lmap1, 16, bs) RUN_GATE(lmap1, 17, bs)
#pragma unroll
    for (unsigned j = 0; j < 8; ++j) {  // b128: offsets +2q+e
      float4 w4;
      w4.x = v2[2 * j].x; w4.y = v2[2 * j].y;
      w4.z = v2[2 * j + 1].x; w4.w = v2[2 * j + 1].y;
      F4[a1(i1(t, 2 * j, 0)) >> 2] = w4;
    }
  }
  __syncthreads();  // A

  // ---------------- Phase 2: span {5..9} ----------------
  {
    const unsigned bs = base2(t);
#pragma unroll
    for (unsigned p = 0; p < NF2; ++p) v2[p] = Fv[a1(i2(t, p, 0)) >> 1];  // b64
    RUN_GATE(lmap2, 18, bs) RUN_GATE(lmap2, 19, bs)
    RUN_GATE(lmap2, 20, bs) RUN_GATE(lmap2, 21, bs)
  }
  __syncthreads();  // B: T1 reads drained before storage reuse
  {
#pragma unroll
    for (unsigned j = 0; j < 8; ++j) {  // b128: offsets +q+2e
      float4 w4;
      w4.x = v2[2 * j].x; w4.y = v2[2 * j + 1].x;
      w4.z = v2[2 * j].y; w4.w = v2[2 * j + 1].y;
      F4[a2(i2(t, 2 * j, 0)) >> 2] = w4;
    }
  }
  __syncthreads();  // C

  // ---------------- Phase 3: span {1..5} ----------------
  {
    const unsigned bs = base3(t);
#pragma unroll
    for (unsigned p = 0; p < NF2; ++p) v2[p] = Fv[a2(i3(t, p, 0)) >> 1];  // b64
    RUN_GATE(lmap3, 22, bs) RUN_GATE(lmap3, 23, bs)
    RUN_GATE(lmap3, 24, bs) RUN_GATE(lmap3, 25, bs)
  }
  __syncthreads();  // D: T2 reads drained
  {
#pragma unroll
    for (unsigned j = 0; j < 4; ++j) {  // b128 x2: offsets +q, e fixed per store
      float4 w0, w1;
      w0.x = v2[4 * j].x; w0.y = v2[4 * j + 1].x; w0.z = v2[4 * j + 2].x; w0.w = v2[4 * j + 3].x;
      w1.x = v2[4 * j].y; w1.y = v2[4 * j + 1].y; w1.z = v2[4 * j + 2].y; w1.w = v2[4 * j + 3].y;
      F4[a3(i3(t, 4 * j, 0)) >> 2] = w0;
      F4[a3(i3(t, 4 * j, 1)) >> 2] = w1;
    }
  }
  __syncthreads();  // E

  // -------- Phase 4: span {0,1,2,12,13} + measurement --------
  float ex[NQ];
  {
    const unsigned bs = base4(t);
#pragma unroll
    for (unsigned j = 0; j < 8; ++j) {  // b128: offsets +2q+e
      const float4 r4 = F4[a3(i4(t, 2 * j, 0)) >> 2];
      v2[2 * j] = mk2(r4.x, r4.y);
      v2[2 * j + 1] = mk2(r4.z, r4.w);
    }
    RUN_GATE(lmap4, 26, bs) RUN_GATE(lmap4, 27, bs)

    // q = v^2; WHT over p bits; e-level folded into extraction
#pragma unroll
    for (unsigned p = 0; p < NF2; ++p) v2[p] = v2[p] * v2[p];
#pragma unroll
    for (int k = 0; k < 4; ++k) {
      const unsigned K = 1u << k;
#pragma unroll
      for (unsigned p = 0; p < NF2; ++p) {
        if (p & K) continue;
        const f32x2 A = v2[p], Bv = v2[p ^ K];
        v2[p] = A + Bv;
        v2[p ^ K] = A - Bv;
      }
    }
#pragma unroll
    for (int w = 0; w < NQ; ++w) {
      const unsigned ls = lmap4(SC.fr[w]);
      const f32x2 W = v2[ls >> 1];
      const float coef = (ls & 1u) ? (W.x - W.y) : (W.x + W.y);
      const int tf = __builtin_popcount(bs & SC.fr[w]) & 1;
      ex[w] = tf ? -coef : coef;
    }
  }

  // ---------------- block reduction (8 waves) ----------------
#pragma unroll
  for (int w = 0; w < NQ; ++w) {
#pragma unroll
    for (int off = 32; off > 0; off >>= 1) ex[w] += __shfl_xor(ex[w], off, 64);
  }
  __syncthreads();  // F: T3 reads drained; S reusable
  const unsigned lane = t & 63u, wv = t >> 6;
  if (lane == 0) {
#pragma unroll
    for (int w = 0; w < NQ; ++w) S[wv * NQ + w] = ex[w];
  }
  __syncthreads();  // G
  if (t < NQ) {
    float r = 0.0f;
#pragma unroll
    for (int W = 0; W < 8; ++W) r += S[W * NQ + t];
    out[b * NQ + t] = r;
  }
#undef RUN_GATE
}

extern "C" void kernel_launch(void* const* d_in, const int* in_sizes, int n_in,
                              void* d_out, int out_size, void* d_ws, size_t ws_size,
                              hipStream_t stream) {
  const float* x = (const float*)d_in[0];        // (B, 14) fp32
  const float* weights = (const float*)d_in[1];  // (2, 14) fp32
  float* out = (float*)d_out;                    // (B, 14) fp32
  const int B = in_sizes[0] / NQ;
  qnn_kernel<<<B, BLOCK, 0, stream>>>(x, weights, out);
}

// Round 8
// 61.816 us; speedup vs baseline: 1.1159x; 1.0650x over previous
//
#include <hip/hip_runtime.h>

#define NQ 14
#define BLOCK 256
#define NG 28
#define NF2 32  // f32x2 regs per thread (64 amps)

typedef float f32x2 __attribute__((ext_vector_type(2)));
__device__ __forceinline__ f32x2 mk2(float a, float b) { f32x2 r; r.x = a; r.y = b; return r; }

// ---------------- compile-time schedule (lazy-CNOT folding) ----------------
struct Sched { unsigned m[NG]; unsigned r[NG]; unsigned fr[NQ]; };

constexpr Sched build_sched() {
  Sched sc{};
  unsigned col[NQ] = {}, rowinv[NQ] = {};
  for (int p = 0; p < NQ; ++p) { col[p] = 1u << p; rowinv[p] = 1u << p; }
  int g = 0;
  for (int l = 0; l < 2; ++l) {
    for (int w = 0; w < NQ; ++w) { int p = NQ - 1 - w; sc.m[g] = col[p]; sc.r[g] = rowinv[p]; ++g; }
    for (int w = 0; w < NQ; ++w) {
      int tgt = (w + 1) % NQ; int pc = NQ - 1 - w, pt = NQ - 1 - tgt;
      col[pc] ^= col[pt]; rowinv[pt] ^= rowinv[pc];
    }
  }
  for (int w = 0; w < NQ; ++w) sc.fr[w] = rowinv[NQ - 1 - w];
  return sc;
}
constexpr Sched SC = build_sched();

// Layer-0 weights absorbed into fill. Remaining 14 gates, R5's proven buckets:
constexpr int QA_G[4] = {15, 16, 17, 18};
constexpr int QB_G[5] = {19, 20, 21, 22, 23};
constexpr int QC_G[5] = {14, 24, 25, 26, 27};

// local maps: l = (p<<1)|e
constexpr unsigned lmapA(unsigned v) { return (v >> 8) & 63u; }                              // e=i8, p=i9..13
constexpr unsigned lmapB(unsigned v) { return ((v >> 8) & 1u) | (((v >> 3) & 31u) << 1); }   // e=i8, p=i3..7
constexpr unsigned lmapC(unsigned v) {                                                       // e=i3, p=i0..2,i12,13
  return ((v >> 3) & 1u) | ((v & 7u) << 1) | (((v >> 12) & 3u) << 4);
}

// ---------------- schedule legality (machine-checked) ----------------
constexpr bool sched_ok() {
  for (int g = 0; g < 14; ++g)
    if (SC.m[g] != (1u << (13 - g)) || SC.r[g] != (1u << (13 - g))) return false;
  const unsigned spanA = 0x3F00u, spanB = 0x01F8u, spanC = 0x300Fu;
  for (int k = 0; k < 4; ++k) {
    if (SC.m[QA_G[k]] & ~spanA) return false;
    if (!(__builtin_popcount(lmapA(SC.m[QA_G[k]]) & lmapA(SC.r[QA_G[k]])) & 1)) return false;
  }
  for (int k = 0; k < 5; ++k) {
    if (SC.m[QB_G[k]] & ~spanB) return false;
    if (!(__builtin_popcount(lmapB(SC.m[QB_G[k]]) & lmapB(SC.r[QB_G[k]])) & 1)) return false;
  }
  for (int k = 0; k < 5; ++k) {
    if (SC.m[QC_G[k]] & ~spanC) return false;
    if (!(__builtin_popcount(lmapC(SC.m[QC_G[k]]) & lmapC(SC.r[QC_G[k]])) & 1)) return false;
  }
  int ord[14] = {}; int n = 0;
  for (int k = 0; k < 4; ++k) ord[n++] = QA_G[k];
  for (int k = 0; k < 5; ++k) ord[n++] = QB_G[k];
  for (int k = 0; k < 5; ++k) ord[n++] = QC_G[k];
  for (int g = 14; g < NG; ++g) { int c = 0; for (int i = 0; i < 14; ++i) if (ord[i] == g) ++c; if (c != 1) return false; }
  for (int i = 0; i < 14; ++i)
    for (int j = i + 1; j < 14; ++j)
      if (ord[i] > ord[j]) {
        int a = ord[i], b = ord[j];
        if ((__builtin_popcount(SC.r[a] & SC.m[b]) & 1) != (__builtin_popcount(SC.r[b] & SC.m[a]) & 1)) return false;
      }
  return true;
}
static_assert(sched_ok(), "schedule invalid");

// ---------- phase layouts: (t<256, p<32, e<2) -> state i ----------
__host__ __device__ constexpr unsigned iQA(unsigned t, unsigned p, unsigned e) {
  return t | (e << 8) | (p << 9);
}
__host__ __device__ constexpr unsigned iQB(unsigned t, unsigned p, unsigned e) {
  return (t & 7u) | (p << 3) | (e << 8) | ((t >> 3) << 9);
}
__host__ __device__ constexpr unsigned iQC(unsigned t, unsigned p, unsigned e) {
  return (p & 7u) | (e << 3) | (t << 4) | ((p >> 3) << 12);
}

// ---------- canonical storage maps (dword address of state i) ----------
__host__ __device__ constexpr unsigned dwT1(unsigned i) {  // T1: QA -> QB
  const unsigned low5 = ((i >> 9) & 31u) ^ (i & 30u) ^ ((i & 3u) << 3);
  return 2u * (low5 | ((i & 255u) << 5)) + ((i >> 8) & 1u);
}
__host__ __device__ constexpr unsigned dwT2(unsigned i) {  // T2: QB -> QC
  const unsigned rest = (((i >> 4) & 15u) ^ (i & 7u)) | ((i & 7u) << 4) | (((i >> 9) & 31u) << 7);
  return ((i >> 3) & 1u) | (((i >> 8) & 1u) << 1) | (rest << 2);
}

// ---------- device base / compile-time-offset decompositions ----------
__host__ __device__ constexpr unsigned BASEW1(unsigned t) {  // f32x2-slot units
  return ((t & 30u) ^ ((t & 3u) << 3)) | (t << 5);
}
__host__ __device__ constexpr unsigned BASER1(unsigned t) {
  return ((t >> 3) ^ (t & 6u) ^ ((t & 3u) << 3)) | ((t & 7u) << 5);
}
__host__ __device__ constexpr unsigned VR1(unsigned p) { return ((p & 3u) << 3) | (p << 8); }
__host__ __device__ constexpr unsigned CW2(unsigned t) {  // dword units
  return ((t & 7u) << 2) | ((t & 7u) << 6) | ((t >> 3) << 9);
}
__host__ __device__ constexpr unsigned VW2(unsigned p, unsigned e) {
  return (p & 1u) | (e << 1) | ((p >> 1) << 2);
}
__host__ __device__ constexpr unsigned CR2(unsigned t) {
  return (((t >> 4) & 1u) << 1) | ((t & 15u) << 2) | ((t >> 5) << 9);
}
__host__ __device__ constexpr unsigned VR2(unsigned p, unsigned e) {
  return e | ((p & 7u) << 2) | ((p & 7u) << 6) | ((p >> 3) << 12);
}

// ---------------- machine checks ----------------
constexpr bool layouts_ok() {
  for (int mapi = 0; mapi < 3; ++mapi) {
    unsigned acc = 0;
    for (int k = 0; k < 14; ++k) {
      unsigned t = 0, p = 0, e = 0;
      if (k < 8) t = 1u << k; else if (k < 13) p = 1u << (k - 8); else e = 1;
      const unsigned v = (mapi == 0) ? iQA(t, p, e) : (mapi == 1) ? iQB(t, p, e) : iQC(t, p, e);
      if (__builtin_popcount(v) != 1 || (acc & v)) return false;
      acc |= v;
    }
    if (acc != 0x3FFFu) return false;
  }
  return true;
}
static_assert(layouts_ok(), "phase layouts invalid");

constexpr bool stmap_bij(int which) {
  bool hit[16384] = {};
  for (unsigned i = 0; i < 16384; ++i) {
    const unsigned a = which == 0 ? dwT1(i) : dwT2(i);
    if (a >= 16384u || hit[a]) return false;
    hit[a] = true;
  }
  return true;
}
static_assert(stmap_bij(0), "dwT1 not bijective");
static_assert(stmap_bij(1), "dwT2 not bijective");

// device decomposition == canonical map, exhaustive
constexpr bool chkT1(unsigned t0, unsigned t1) {
  for (unsigned t = t0; t < t1; ++t) {
    for (unsigned k = 0; k < 16; ++k) {  // writer float4: dwords {2k.x,2k.y,2k+1.x,2k+1.y}
      const unsigned B = 4u * ((BASEW1(t) >> 1) ^ k);
      if (B + 3 >= 16384u) return false;
      if (dwT1(iQA(t, 2 * k, 0)) != B) return false;
      if (dwT1(iQA(t, 2 * k, 1)) != B + 1) return false;
      if (dwT1(iQA(t, 2 * k + 1, 0)) != B + 2) return false;
      if (dwT1(iQA(t, 2 * k + 1, 1)) != B + 3) return false;
    }
    for (unsigned p = 0; p < 32; ++p)  // reader b64
      for (unsigned e = 0; e < 2; ++e)
        if (dwT1(iQB(t, p, e)) != 2u * (BASER1(t) ^ VR1(p)) + e) return false;
  }
  return true;
}
static_assert(chkT1(0, 64) && chkT1(64, 128), "T1 addr 0-128");
static_assert(chkT1(128, 192) && chkT1(192, 256), "T1 addr 128-256");

constexpr bool chkT2(unsigned t0, unsigned t1) {
  for (unsigned t = t0; t < t1; ++t) {
    for (unsigned k = 0; k < 16; ++k) {  // writer float4: dwords {2k.x,2k+1.x,2k.y,2k+1.y}
      const unsigned B = 4u * ((CW2(t) >> 2) ^ k);
      if (B + 3 >= 16384u) return false;
      for (unsigned q = 0; q < 2; ++q)
        for (unsigned e = 0; e < 2; ++e)
          if (dwT2(iQB(t, 2 * k + q, e)) != B + q + 2 * e) return false;
    }
    for (unsigned p = 0; p < 32; ++p)  // reader b64
      for (unsigned e = 0; e < 2; ++e)
        if (dwT2(iQC(t, p, e)) != (CR2(t) ^ VR2(p, 0)) + e) return false;
  }
  return true;
}
static_assert(chkT2(0, 64) && chkT2(64, 128), "T2 addr 0-128");
static_assert(chkT2(128, 192) && chkT2(192, 256), "T2 addr 128-256");

// bank balance at the bandwidth floor (hand-derived, asserted exactly)
constexpr bool banks_ok() {
  for (unsigned W = 0; W < 4; ++W) {
    for (unsigned k = 0; k < 16; ++k) {  // T1w b128: group=(slot>>1)&7; T2w b128: group=(d>>2)&7
      int c1[8] = {}, c2[8] = {};
      for (unsigned l = 0; l < 64; ++l) {
        const unsigned t = W * 64u + l;
        if (++c1[((BASEW1(t) ^ (2u * k)) >> 1) & 7u] > 8) return false;
        if (++c2[((CW2(t) >> 2) ^ k) & 7u] > 8) return false;
      }
    }
    for (unsigned p = 0; p < 32; ++p) {  // T1r b64: pair=slot&15; T2r b64: pair=(d>>1)&15
      int c1[16] = {}, c2[16] = {};
      for (unsigned l = 0; l < 64; ++l) {
        const unsigned t = W * 64u + l;
        if (++c1[(BASER1(t) ^ VR1(p)) & 15u] > 4) return false;
        if (++c2[((CR2(t) ^ VR2(p, 0)) >> 1) & 15u] > 4) return false;
      }
    }
  }
  return true;
}
static_assert(banks_ok(), "bank balance");

// ---------------- packed register butterfly (6-bit local) ----------------
template <unsigned MU, unsigned RHO>
__device__ __forceinline__ void gate_pk(f32x2* v, const float cg, const float sb) {
  const f32x2 C = mk2(cg, cg);
  constexpr unsigned M2 = MU >> 1;
  constexpr bool ODD = (MU & 1u) != 0;
  if constexpr (!ODD) {
    constexpr unsigned LSB = M2 & (0u - M2);
#pragma unroll
    for (unsigned p = 0; p < NF2; ++p) {
      if (p & LSB) continue;
      const unsigned q = p ^ M2;
      const int s0 = __builtin_popcount((2u * p) & RHO) & 1;
      const int s1 = __builtin_popcount((2u * p + 1u) & RHO) & 1;
      const f32x2 Sp = mk2(s0 ? -sb : sb, s1 ? -sb : sb);
      const f32x2 Xp = v[p], Xq = v[q];
      v[p] = C * Xp - Sp * Xq;
      v[q] = C * Xq + Sp * Xp;
    }
  } else if constexpr (M2 == 0) {
#pragma unroll
    for (unsigned p = 0; p < NF2; ++p) {
      const int s0 = __builtin_popcount((2u * p) & RHO) & 1;
      const f32x2 Sp = mk2(s0 ? -sb : sb, s0 ? sb : -sb);
      const f32x2 X = v[p];
      v[p] = C * X - Sp * mk2(X.y, X.x);
    }
  } else {
    constexpr unsigned LSB = M2 & (0u - M2);
#pragma unroll
    for (unsigned p = 0; p < NF2; ++p) {
      if (p & LSB) continue;
      const unsigned q = p ^ M2;
      const int s0 = __builtin_popcount((2u * p) & RHO) & 1;
      const int s1 = __builtin_popcount((2u * p + 1u) & RHO) & 1;
      const f32x2 Sp = mk2(s0 ? -sb : sb, s1 ? -sb : sb);
      const f32x2 Xp = v[p], Xq = v[q];
      const f32x2 T = Sp * Xp;
      v[p] = C * Xp - Sp * mk2(Xq.y, Xq.x);
      v[q] = C * Xq + mk2(T.y, T.x);
    }
  }
}

__global__ __launch_bounds__(BLOCK, 2) void qnn_kernel(
    const float* __restrict__ x, const float* __restrict__ wts,
    float* __restrict__ out) {
  __shared__ float4 S4[4096];  // 64 KB
  float* const S = (float*)S4;
  float4* const F4 = S4;
  f32x2* const Fv = (f32x2*)S4;
  const unsigned t = threadIdx.x;
  const int b = blockIdx.x;

  f32x2 v2[NF2];

  // ---- Fill: RY(x + weights[0]) product state, QA layout (R4/R5-verified) ----
  {
    float cxx[NQ], sxx[NQ];
#pragma unroll
    for (int w = 0; w < NQ; ++w)
      __sincosf(0.5f * (x[b * NQ + w] + wts[w]), &sxx[w], &cxx[w]);
    float pl = 1.0f;
#pragma unroll
    for (int bb = 0; bb < 8; ++bb) pl *= ((t >> bb) & 1) ? sxx[13 - bb] : cxx[13 - bb];
    v2[0] = mk2(pl * cxx[5], pl * sxx[5]);  // e = i8 = wire 5
#pragma unroll
    for (int k = 1; k < 6; ++k) {  // p bit k-1 = i bit 8+k = wire 5-k
      const unsigned K = 1u << (k - 1);
      const f32x2 sk = mk2(sxx[5 - k], sxx[5 - k]);
      const f32x2 ck = mk2(cxx[5 - k], cxx[5 - k]);
#pragma unroll
      for (unsigned p = 0; p < 16; ++p) {
        if (p & ~(K - 1u)) continue;
        v2[p | K] = v2[p] * sk;
        v2[p] = v2[p] * ck;
      }
    }
  }

#define RUN_GATE(LM, G, BASEPAR)                                          \
  {                                                                       \
    float sn, cs;                                                         \
    __sincosf(0.5f * wts[G], &sn, &cs);                                   \
    const float sb =                                                      \
        (__builtin_popcount((BASEPAR) & SC.r[G]) & 1) ? -sn : sn;         \
    gate_pk<LM(SC.m[G]), LM(SC.r[G])>(v2, cs, sb);                        \
  }

  // ---------------- Phase QA ----------------
  {
    const unsigned bs = t;
    RUN_GATE(lmapA, QA_G[0], bs) RUN_GATE(lmapA, QA_G[1], bs)
    RUN_GATE(lmapA, QA_G[2], bs) RUN_GATE(lmapA, QA_G[3], bs)
    const unsigned w1 = BASEW1(t) >> 1;  // float4 index base
#pragma unroll
    for (unsigned k = 0; k < 16; ++k) {
      float4 w4;
      w4.x = v2[2 * k].x; w4.y = v2[2 * k].y;
      w4.z = v2[2 * k + 1].x; w4.w = v2[2 * k + 1].y;
      F4[w1 ^ k] = w4;
    }
  }
  __syncthreads();  // A

  // ---------------- Phase QB ----------------
  {
    const unsigned bs = (t & 7u) | ((t >> 3) << 9);
    const unsigned r1 = BASER1(t);
#pragma unroll
    for (unsigned p = 0; p < 32; ++p) v2[p] = Fv[r1 ^ VR1(p)];
    RUN_GATE(lmapB, QB_G[0], bs) RUN_GATE(lmapB, QB_G[1], bs)
    RUN_GATE(lmapB, QB_G[2], bs) RUN_GATE(lmapB, QB_G[3], bs)
    RUN_GATE(lmapB, QB_G[4], bs)
  }
  __syncthreads();  // B: T1 reads drained
  {
    const unsigned w2 = CW2(t) >> 2;  // float4 index base
#pragma unroll
    for (unsigned k = 0; k < 16; ++k) {
      float4 w4;
      w4.x = v2[2 * k].x; w4.y = v2[2 * k + 1].x;
      w4.z = v2[2 * k].y; w4.w = v2[2 * k + 1].y;
      F4[w2 ^ k] = w4;
    }
  }
  __syncthreads();  // C

  // ---------------- Phase QC + measurement ----------------
  float ex[NQ];
  {
    const unsigned bs = t << 4;
    const unsigned r2 = CR2(t);
#pragma unroll
    for (unsigned p = 0; p < 32; ++p) v2[p] = Fv[(r2 ^ VR2(p, 0)) >> 1];
    RUN_GATE(lmapC, QC_G[0], bs) RUN_GATE(lmapC, QC_G[1], bs)
    RUN_GATE(lmapC, QC_G[2], bs) RUN_GATE(lmapC, QC_G[3], bs)
    RUN_GATE(lmapC, QC_G[4], bs)

    // q = v^2; WHT over 5 p-bits; e folded into extraction
#pragma unroll
    for (unsigned p = 0; p < NF2; ++p) v2[p] = v2[p] * v2[p];
#pragma unroll
    for (int k = 0; k < 5; ++k) {
      const unsigned K = 1u << k;
#pragma unroll
      for (unsigned p = 0; p < NF2; ++p) {
        if (p & K) continue;
        const f32x2 A = v2[p], Bv = v2[p ^ K];
        v2[p] = A + Bv;
        v2[p ^ K] = A - Bv;
      }
    }
#pragma unroll
    for (int w = 0; w < NQ; ++w) {
      const unsigned ls = lmapC(SC.fr[w]);
      const f32x2 W = v2[ls >> 1];
      const float coef = (ls & 1u) ? (W.x - W.y) : (W.x + W.y);
      const int tf = __builtin_popcount(bs & SC.fr[w]) & 1;
      ex[w] = tf ? -coef : coef;
    }
  }
  __syncthreads();  // D: T2 reads drained; S reusable

  // ---------------- two-stage LDS reduction ----------------
  // Stage A: ex[w] at dword t*16 + ((w&14)^(t&14)) + (w&1); 7 b64 writes
  {
    const unsigned fb = t * 8u + ((t >> 1) & 7u);  // Fv idx = t*8 + (q ^ ((t>>1)&7))
#pragma unroll
    for (unsigned q = 0; q < 7; ++q) Fv[(fb ^ ((t >> 1) & 7u)) ^ (q ^ 0u) + 0u];  // (no-op guard removed below)
#pragma unroll
    for (unsigned q = 0; q < 7; ++q)
      Fv[t * 8u + (q ^ ((t >> 1) & 7u))] = mk2(ex[2 * q], ex[2 * q + 1]);
  }
  __syncthreads();  // E
  {
    const unsigned w = t & 15u, g = t >> 4;
    if (w < NQ) {
      float acc = 0.0f;
#pragma unroll
      for (unsigned k = 0; k < 16; ++k)
        acc += S[(g * 16u + k) * 16u + (((w & 14u) ^ (k & 14u)) + (w & 1u))];
      S[8192u + w * 16u + g] = acc;
    }
  }
  __syncthreads();  // F
  if (t < NQ) {
    float r = 0.0f;
#pragma unroll
    for (unsigned j = 0; j < 4; ++j) {
      const float4 r4 = F4[2048u + t * 4u + j];
      r += r4.x + r4.y + r4.z + r4.w;
    }
    out[b * NQ + t] = r;
  }
#undef RUN_GATE
}

extern "C" void kernel_launch(void* const* d_in, const int* in_sizes, int n_in,
                              void* d_out, int out_size, void* d_ws, size_t ws_size,
                              hipStream_t stream) {
  const float* x = (const float*)d_in[0];        // (B, 14) fp32
  const float* weights = (const float*)d_in[1];  // (2, 14) fp32
  float* out = (float*)d_out;                    // (B, 14) fp32
  const int B = in_sizes[0] / NQ;
  qnn_kernel<<<B, BLOCK, 0, stream>>>(x, weights, out);
}